// Round 8
// baseline (309.748 us; speedup 1.0000x reference)
//
#include <hip/hip_runtime.h>
#include <hip/hip_bf16.h>
#include <math.h>

// ---------------- types ----------------
typedef short s16x8 __attribute__((ext_vector_type(8)));
typedef float f32x4 __attribute__((ext_vector_type(4)));

// ---------------- fp32 <-> bf16 ----------------
__device__ inline unsigned short f2bf(float x) {
    unsigned int u = __float_as_uint(x);
    unsigned int r = (u + 0x7fffu + ((u >> 16) & 1u)) >> 16;
    return (unsigned short)r;
}
__device__ inline unsigned int f2bf2(float lo, float hi) {
    return ((unsigned int)f2bf(hi) << 16) | (unsigned int)f2bf(lo);
}
__device__ inline float bf2f(unsigned short u) {
    return __uint_as_float(((unsigned int)u) << 16);
}

// fast tanh: 1 - 2/(exp(2x)+1); saturates correctly at +-inf
__device__ inline float fast_tanh(float x) {
    float e = __expf(2.0f * x);
    return 1.0f - 2.0f * __builtin_amdgcn_rcpf(e + 1.0f);
}

// ---------------- prep: cvt W_ih -> bf16, pack W_lin -> bf16 [16][2336] ------
__global__ void prep_kernel(const float* __restrict__ W_ih,
                            const float* __restrict__ W_lin,
                            unsigned short* __restrict__ wb,
                            unsigned short* __restrict__ wlb) {
    int blk = blockIdx.x;
    int tid = threadIdx.x;
    if (blk < 4096) {
        int i = blk * 256 + tid;
        float4 v = ((const float4*)W_ih)[i];
        ushort4 o; o.x = f2bf(v.x); o.y = f2bf(v.y); o.z = f2bf(v.z); o.w = f2bf(v.w);
        ((ushort4*)wb)[i] = o;
    } else {
        int idx = (blk - 4096) * 256 + tid;   // 16*2336 = 37376
        if (idx < 37376) {
            int c = idx / 2336, k = idx - c * 2336;
            float v = (c < 10 && k < 2318) ? W_lin[c * 2318 + k] : 0.f;
            wlb[idx] = f2bf(v);
        }
    }
}

// ---------------- GEMM: Hb = bf16(tanh(x @ W_ih^T + b)) ----------------
// A = x fp32 (8192,2048) converted in-kernel; B = wb bf16 (2048,2048).
// BK=32, 128x128 tile, 256 thr (2x2 waves of 64x64), 16x16x32 MFMA.
// grid (x=col 16, y=row 64): 1 MB fp32 x-stripe shared by 16 col-blocks (L2).
// LDS 16B-chunk swizzle slot = c ^ ((r>>1)&3): conflict-free (validated: 0).
// A fp32 loads hoisted BEFORE first barrier -> overlap prior iter's MFMA.
__global__ __launch_bounds__(256) void gemm_tanh_kernel(
    const float* __restrict__ Ax, const unsigned short* __restrict__ Bm,
    const float* __restrict__ b_ih, const float* __restrict__ b_hh,
    unsigned short* __restrict__ Hb)
{
    __shared__ unsigned short As[128 * 32];  // 8 KB
    __shared__ unsigned short Bs[128 * 32];  // 8 KB

    const int tid  = threadIdx.x;
    const int lane = tid & 63;
    const int wave = tid >> 6;
    const int col0 = blockIdx.x * 128;
    const int row0 = blockIdx.y * 128;
    const int wr = (wave >> 1) * 64;
    const int wc = (wave & 1) * 64;
    const int quad = lane >> 4;
    const int mrow = lane & 15;

    f32x4 acc[4][4];
#pragma unroll
    for (int i = 0; i < 4; ++i)
#pragma unroll
        for (int j = 0; j < 4; ++j)
            acc[i][j] = f32x4{0.f, 0.f, 0.f, 0.f};

    for (int k0 = 0; k0 < 2048; k0 += 32) {
        // A fp32 loads into regs (no LDS touch) - overlaps prior MFMA tail
        float4 fa[2][2];
#pragma unroll
        for (int i = 0; i < 2; ++i) {
            int c = i * 256 + tid;
            int r = c >> 2, c4 = c & 3;
            int cg = c4 ^ ((r >> 1) & 3);
            const float* gp = Ax + (size_t)(row0 + r) * 2048 + k0 + cg * 8;
            fa[i][0] = *(const float4*)gp;
            fa[i][1] = *(const float4*)(gp + 4);
        }
        __syncthreads();   // prior iter's ds_reads done before LDS overwrite
#pragma unroll
        for (int i = 0; i < 2; ++i) {
            int c = i * 256 + tid;
            uint4 q;
            q.x = f2bf2(fa[i][0].x, fa[i][0].y);
            q.y = f2bf2(fa[i][0].z, fa[i][0].w);
            q.z = f2bf2(fa[i][1].x, fa[i][1].y);
            q.w = f2bf2(fa[i][1].z, fa[i][1].w);
            *(uint4*)(&As[c * 8]) = q;     // 16B LDS store, swizzled layout
        }
#pragma unroll
        for (int i = 0; i < 2; ++i) {
            int t = i * 256 + tid;
            int r = t >> 2, c = t & 3;
            int cg = c ^ ((r >> 1) & 3);
            const unsigned short* gp = Bm + (size_t)(col0 + r) * 2048 + k0 + cg * 8;
            __builtin_amdgcn_global_load_lds(
                (const __attribute__((address_space(1))) void*)gp,
                (__attribute__((address_space(3))) void*)(&Bs[t * 8]), 16, 0, 0);
        }
        __syncthreads();

        s16x8 af[4], bfr[4];
#pragma unroll
        for (int i = 0; i < 4; ++i) {
            int R = wr + i * 16 + mrow;
            int slot = quad ^ ((R >> 1) & 3);
            af[i] = *(const s16x8*)(&As[R * 32 + slot * 8]);
        }
#pragma unroll
        for (int j = 0; j < 4; ++j) {
            int R = wc + j * 16 + mrow;
            int slot = quad ^ ((R >> 1) & 3);
            bfr[j] = *(const s16x8*)(&Bs[R * 32 + slot * 8]);
        }
#pragma unroll
        for (int i = 0; i < 4; ++i)
#pragma unroll
            for (int j = 0; j < 4; ++j)
                acc[i][j] = __builtin_amdgcn_mfma_f32_16x16x32_bf16(
                    af[i], bfr[j], acc[i][j], 0, 0, 0);
    }

    float bias[4];
#pragma unroll
    for (int j = 0; j < 4; ++j) {
        int gc = col0 + wc + j * 16 + mrow;
        bias[j] = b_ih[gc] + b_hh[gc];
    }
#pragma unroll
    for (int i = 0; i < 4; ++i) {
#pragma unroll
        for (int r = 0; r < 4; ++r) {
            int grow = row0 + wr + i * 16 + quad * 4 + r;
#pragma unroll
            for (int j = 0; j < 4; ++j) {
                int gc = col0 + wc + j * 16 + mrow;
                float v = acc[i][j][r] + bias[j];
                Hb[(size_t)grow * 2048 + gc] = f2bf(fast_tanh(v));
            }
        }
    }
}

// ---------------- AvgPool1d(k=45,s=45): 8 rows/block, coalesced f-major out --
__global__ __launch_bounds__(256) void pool_kernel(
    const unsigned short* __restrict__ Hb, float* __restrict__ pooled_t) {
    __shared__ unsigned short hs[8 * 2048];  // 32 KB
    __shared__ float outs[45 * 8];
    int b0 = blockIdx.x * 8;
    int tid = threadIdx.x;
    const ushort4* src = (const ushort4*)(Hb + (size_t)b0 * 2048);
    ushort4* dst = (ushort4*)hs;
    for (int i = tid; i < 4096; i += 256) dst[i] = src[i];
    __syncthreads();
    for (int o = tid; o < 360; o += 256) {
        int f = o % 45, r = o / 45;
        const unsigned short* row = hs + r * 2048 + f * 45;
        float s = 0.f;
#pragma unroll
        for (int k = 0; k < 45; ++k) s += bf2f(row[k]);
        outs[f * 8 + r] = s * (1.0f / 45.0f);
    }
    __syncthreads();
    for (int o = tid; o < 360; o += 256) {
        int f = o >> 3, r = o & 7;
        pooled_t[f * 8192 + b0 + r] = outs[o];
    }
}

// ---------------- per-feature dual prefix sum (sum, sum^2), single pass ------
__global__ __launch_bounds__(256) void scan_kernel(
    const float* __restrict__ pooled_t,
    float* __restrict__ cs_t, float* __restrict__ cs2_t) {
    __shared__ float t1[256], t2[256];
    int f = blockIdx.x;
    int tid = threadIdx.x;
    const float* p = pooled_t + f * 8192;
    int base = tid * 32;
    float loc[32];
    float s1 = 0.f, s2 = 0.f;
#pragma unroll
    for (int i = 0; i < 32; ++i) {
        float v = p[base + i];
        loc[i] = v; s1 += v; s2 += v * v;
    }
    t1[tid] = s1; t2[tid] = s2;
    __syncthreads();
    for (int d = 1; d < 256; d <<= 1) {
        float a1 = (tid >= d) ? t1[tid - d] : 0.f;
        float a2 = (tid >= d) ? t2[tid - d] : 0.f;
        __syncthreads();
        t1[tid] += a1; t2[tid] += a2;
        __syncthreads();
    }
    float r1 = t1[tid] - s1, r2 = t2[tid] - s2;  // exclusive offsets
    float* c1 = cs_t + f * 8192;
    float* c2 = cs2_t + f * 8192;
#pragma unroll
    for (int i = 0; i < 32; ++i) {
        float v = loc[i];
        r1 += v; r2 += v * v;
        c1[base + i] = r1; c2[base + i] = r2;
    }
}

// ---------------- final: MFMA GEMM [Hb|est](8192x2336) @ Wb^T(16x2336) -------
// 32 rows/block, 256 blocks. Es tile built from L2-hot cs_t/cs2_t.
#define ESTRIDE 290
__global__ __launch_bounds__(256) void final_kernel(
    const unsigned short* __restrict__ Hb,
    const float* __restrict__ cs_t, const float* __restrict__ cs2_t,
    const unsigned short* __restrict__ Wb, const float* __restrict__ b_lin,
    float* __restrict__ out) {
    __shared__ unsigned short Es[32 * ESTRIDE];  // 18.1 KB
    __shared__ float comb[2 * 16 * 17];          // 2.1 KB
    int tid = threadIdx.x;
    int lane = tid & 63;
    int wave = tid >> 6;
    int b0 = blockIdx.x * 32;

    for (int i = tid; i < 135 * 32; i += 256) {
        int fj = i >> 5, r = i & 31;
        int f = fj / 3, j = fj - 3 * f;
        int b = b0 + r;
        int L = (j == 0) ? 32 : (j == 1) ? 128 : 512;
        const float* c1 = cs_t + f * 8192;
        const float* c2 = cs2_t + f * 8192;
        float a1 = c1[b], a2 = c2[b];
        float p1 = 0.f, p2 = 0.f;
        if (b >= L) { p1 = c1[b - L]; p2 = c2[b - L]; }
        float cnt = (float)((b + 1 < L) ? (b + 1) : L);
        float m = (a1 - p1) / cnt;
        float v = (a2 - p2) / cnt - m * m;
        int d0 = f * 6 + j * 2;
        Es[r * ESTRIDE + d0]     = f2bf(m);
        Es[r * ESTRIDE + d0 + 1] = f2bf(v);
    }
    for (int i = tid; i < 32 * 18; i += 256) {
        int r = i / 18, d = 270 + i % 18;
        Es[r * ESTRIDE + d] = 0;
    }
    __syncthreads();

    const int t = wave >> 1;
    const int kh = wave & 1;
    const int quad = lane >> 4;
    const int mrow = lane & 15;
    const int rowt = b0 + t * 16;

    f32x4 acc = f32x4{0.f, 0.f, 0.f, 0.f};
    const unsigned short* arow = Hb + (size_t)(rowt + mrow) * 2048 + kh * 1024 + quad * 8;
    const unsigned short* brow = Wb + (size_t)mrow * 2336 + kh * 1024 + quad * 8;
#pragma unroll 4
    for (int k = 0; k < 1024; k += 32) {
        s16x8 a = *(const s16x8*)(arow + k);
        s16x8 b = *(const s16x8*)(brow + k);
        acc = __builtin_amdgcn_mfma_f32_16x16x32_bf16(a, b, acc, 0, 0, 0);
    }
    if (kh) {
        const unsigned short* erow = Es + (t * 16 + mrow) * ESTRIDE + quad * 8;
        const unsigned short* wrow = Wb + (size_t)mrow * 2336 + 2048 + quad * 8;
#pragma unroll
        for (int k = 0; k < 288; k += 32) {
            s16x8 a = *(const s16x8*)(erow + k);
            s16x8 b = *(const s16x8*)(wrow + k);
            acc = __builtin_amdgcn_mfma_f32_16x16x32_bf16(a, b, acc, 0, 0, 0);
        }
    }

    float* cb = comb + t * 272;
    if (kh == 0) {
#pragma unroll
        for (int r = 0; r < 4; ++r) cb[(quad * 4 + r) * 17 + mrow] = acc[r];
    }
    __syncthreads();
    if (kh == 1) {
#pragma unroll
        for (int r = 0; r < 4; ++r) cb[(quad * 4 + r) * 17 + mrow] += acc[r];
    }
    __syncthreads();

    if (tid < 32) {
        const float* basep = comb + (tid >> 4) * 272 + (tid & 15) * 17;
        float lg[10];
        float mx = -1e30f;
#pragma unroll
        for (int c = 0; c < 10; ++c) {
            lg[c] = basep[c] + b_lin[c];
            mx = fmaxf(mx, lg[c]);
        }
        float s = 0.f;
#pragma unroll
        for (int c = 0; c < 10; ++c) { lg[c] = expf(lg[c] - mx); s += lg[c]; }
        float inv = 1.0f / s;
#pragma unroll
        for (int c = 0; c < 10; ++c) out[(size_t)(b0 + tid) * 10 + c] = lg[c] * inv;
    }
}

// ---------------- launch ----------------
extern "C" void kernel_launch(void* const* d_in, const int* in_sizes, int n_in,
                              void* d_out, int out_size, void* d_ws, size_t ws_size,
                              hipStream_t stream) {
    const float* x     = (const float*)d_in[0];   // (8192,1,2048)
    const float* W_ih  = (const float*)d_in[1];   // (2048,2048)
    // d_in[2] = W_hh unused: h0 == 0 so the recurrent term vanishes
    const float* b_ih  = (const float*)d_in[3];
    const float* b_hh  = (const float*)d_in[4];
    const float* W_lin = (const float*)d_in[5];   // (10, 2318)
    const float* b_lin = (const float*)d_in[6];
    float* out = (float*)d_out;

    char* ws = (char*)d_ws;
    unsigned short* wb  = (unsigned short*)(ws);                 //  8388608 B
    unsigned short* Hb  = (unsigned short*)(ws + 8388608);       // 33554432 B
    float* pooled_t     = (float*)(ws + 41943040);               //  1474560 B
    float* cs_t         = (float*)(ws + 43417600);               //  1474560 B
    float* cs2_t        = (float*)(ws + 44892160);               //  1474560 B
    unsigned short* wlb = (unsigned short*)(ws + 46366720);      //    74752 B (~46.4 MB)

    prep_kernel<<<4243, 256, 0, stream>>>(W_ih, W_lin, wb, wlb);
    dim3 ggrid(16, 64);
    gemm_tanh_kernel<<<ggrid, 256, 0, stream>>>(x, wb, b_ih, b_hh, Hb);
    pool_kernel<<<1024, 256, 0, stream>>>(Hb, pooled_t);
    scan_kernel<<<45, 256, 0, stream>>>(pooled_t, cs_t, cs2_t);
    final_kernel<<<256, 256, 0, stream>>>(Hb, cs_t, cs2_t, wlb, b_lin, out);
}

// Round 9
// 253.854 us; speedup vs baseline: 1.2202x; 1.2202x over previous
//
#include <hip/hip_runtime.h>
#include <hip/hip_bf16.h>
#include <math.h>

// ---------------- types ----------------
typedef short s16x8 __attribute__((ext_vector_type(8)));
typedef float f32x4 __attribute__((ext_vector_type(4)));

// ---------------- fp32 <-> bf16 ----------------
__device__ inline unsigned short f2bf(float x) {
    unsigned int u = __float_as_uint(x);
    unsigned int r = (u + 0x7fffu + ((u >> 16) & 1u)) >> 16;
    return (unsigned short)r;
}
__device__ inline float bf2f(unsigned short u) {
    return __uint_as_float(((unsigned int)u) << 16);
}

// fast tanh: 1 - 2/(exp(2x)+1); saturates correctly at +-inf
__device__ inline float fast_tanh(float x) {
    float e = __expf(2.0f * x);
    return 1.0f - 2.0f * __builtin_amdgcn_rcpf(e + 1.0f);
}

// ---- prep: cvt x, cvt W_ih, pack W_lin -> bf16 [16][2336], zero pooled_t ----
__global__ void prep_kernel(const float* __restrict__ x,
                            const float* __restrict__ W_ih,
                            const float* __restrict__ W_lin,
                            unsigned short* __restrict__ xb,
                            unsigned short* __restrict__ wb,
                            unsigned short* __restrict__ wlb,
                            float* __restrict__ pooled_t) {
    int blk = blockIdx.x;
    int tid = threadIdx.x;
    if (blk < 16384) {
        int i = blk * 256 + tid;
        float4 v = ((const float4*)x)[i];
        ushort4 o; o.x = f2bf(v.x); o.y = f2bf(v.y); o.z = f2bf(v.z); o.w = f2bf(v.w);
        ((ushort4*)xb)[i] = o;
    } else if (blk < 20480) {
        int i = (blk - 16384) * 256 + tid;
        float4 v = ((const float4*)W_ih)[i];
        ushort4 o; o.x = f2bf(v.x); o.y = f2bf(v.y); o.z = f2bf(v.z); o.w = f2bf(v.w);
        ((ushort4*)wb)[i] = o;
    } else if (blk < 20626) {
        int idx = (blk - 20480) * 256 + tid;   // 16*2336 = 37376
        if (idx < 37376) {
            int c = idx / 2336, k = idx - c * 2336;
            float v = (c < 10 && k < 2318) ? W_lin[c * 2318 + k] : 0.f;
            wlb[idx] = f2bf(v);
        }
    } else {
        int idx = (blk - 20626) * 256 + tid;   // 92160 float4 = 368640 floats
        ((float4*)pooled_t)[idx] = float4{0.f, 0.f, 0.f, 0.f};
    }
}

// ---------------- GEMM: Hb = bf16(tanh(x @ W_ih^T + b)) + fused pooling -----
// A = xb bf16 (8192,2048); B = wb bf16 (2048,2048). BK=32, 128x128 tile,
// 256 thr (2x2 waves of 64x64), 16x16x32 MFMA, global_load_lds staging,
// swizzle slot = c ^ ((r>>1)&3) (validated conflict-free).
// Epilogue: two 64-col passes; owning waves write tanh-bf16 to LDS tile
// (stride 66 -> bank-spread row reads), all threads pool the <=3 feature
// segments in the window, atomicAdd partials into pooled_t[f*8192+row].
__global__ __launch_bounds__(256) void gemm_tanh_kernel(
    const unsigned short* __restrict__ A, const unsigned short* __restrict__ Bm,
    const float* __restrict__ b_ih, const float* __restrict__ b_hh,
    unsigned short* __restrict__ Hb, float* __restrict__ pooled_t)
{
    __shared__ unsigned short sbuf[8448];   // 16.9 KB: As(4096)+Bs(4096) / Ps(128*66)
    unsigned short* As = sbuf;
    unsigned short* Bs = sbuf + 4096;
    unsigned short* Ps = sbuf;

    const int tid  = threadIdx.x;
    const int lane = tid & 63;
    const int wave = tid >> 6;
    const int row0 = blockIdx.x * 128;
    const int col0 = blockIdx.y * 128;
    const int wr = (wave >> 1) * 64;
    const int wc = (wave & 1) * 64;
    const int quad = lane >> 4;
    const int mrow = lane & 15;

    f32x4 acc[4][4];
#pragma unroll
    for (int i = 0; i < 4; ++i)
#pragma unroll
        for (int j = 0; j < 4; ++j)
            acc[i][j] = f32x4{0.f, 0.f, 0.f, 0.f};

    for (int k0 = 0; k0 < 2048; k0 += 32) {
        __syncthreads();
#pragma unroll
        for (int i = 0; i < 2; ++i) {
            int t = i * 256 + tid;
            int r = t >> 2, c = t & 3;
            int cg = c ^ ((r >> 1) & 3);
            const unsigned short* gp = A + (size_t)(row0 + r) * 2048 + k0 + cg * 8;
            __builtin_amdgcn_global_load_lds(
                (const __attribute__((address_space(1))) void*)gp,
                (__attribute__((address_space(3))) void*)(&As[t * 8]), 16, 0, 0);
        }
#pragma unroll
        for (int i = 0; i < 2; ++i) {
            int t = i * 256 + tid;
            int r = t >> 2, c = t & 3;
            int cg = c ^ ((r >> 1) & 3);
            const unsigned short* gp = Bm + (size_t)(col0 + r) * 2048 + k0 + cg * 8;
            __builtin_amdgcn_global_load_lds(
                (const __attribute__((address_space(1))) void*)gp,
                (__attribute__((address_space(3))) void*)(&Bs[t * 8]), 16, 0, 0);
        }
        __syncthreads();

        s16x8 af[4], bfr[4];
#pragma unroll
        for (int i = 0; i < 4; ++i) {
            int R = wr + i * 16 + mrow;
            int slot = quad ^ ((R >> 1) & 3);
            af[i] = *(const s16x8*)(&As[R * 32 + slot * 8]);
        }
#pragma unroll
        for (int j = 0; j < 4; ++j) {
            int R = wc + j * 16 + mrow;
            int slot = quad ^ ((R >> 1) & 3);
            bfr[j] = *(const s16x8*)(&Bs[R * 32 + slot * 8]);
        }
#pragma unroll
        for (int i = 0; i < 4; ++i)
#pragma unroll
            for (int j = 0; j < 4; ++j)
                acc[i][j] = __builtin_amdgcn_mfma_f32_16x16x32_bf16(
                    af[i], bfr[j], acc[i][j], 0, 0, 0);
    }

    float bias[4];
#pragma unroll
    for (int j = 0; j < 4; ++j) {
        int gc = col0 + wc + j * 16 + mrow;
        bias[j] = b_ih[gc] + b_hh[gc];
    }

    // two passes over 64-col windows; pass p owned by waves with wc == p*64
#pragma unroll 1
    for (int p = 0; p < 2; ++p) {
        __syncthreads();   // K-loop ds_reads / previous pass pooling done
        if ((wc >> 6) == p) {
#pragma unroll
            for (int i = 0; i < 4; ++i) {
#pragma unroll
                for (int r = 0; r < 4; ++r) {
                    int lrow = wr + i * 16 + quad * 4 + r;
                    int grow = row0 + lrow;
#pragma unroll
                    for (int j = 0; j < 4; ++j) {
                        int lcol = j * 16 + mrow;
                        float v = acc[i][j][r] + bias[j];
                        unsigned short h = f2bf(fast_tanh(v));
                        Hb[(size_t)grow * 2048 + col0 + wc + lcol] = h;
                        Ps[lrow * 66 + lcol] = h;
                    }
                }
            }
        }
        __syncthreads();
        int c0 = col0 + p * 64;
        int f0 = c0 / 45;
        int f1 = (c0 + 63) / 45; if (f1 > 44) f1 = 44;
        int nf = f1 - f0 + 1;
        int ntask = 128 * nf;
        for (int t = tid; t < ntask; t += 256) {
            int row = t / nf;
            int f = f0 + (t - row * nf);
            int clo = f * 45; if (clo < c0) clo = c0;
            int chi = f * 45 + 45;
            if (chi > c0 + 64) chi = c0 + 64;
            if (chi > 2025) chi = 2025;
            if (chi > clo) {
                float s = 0.f;
                for (int c = clo; c < chi; ++c)
                    s += bf2f(Ps[row * 66 + (c - c0)]);
                atomicAdd(&pooled_t[f * 8192 + row0 + row], s * (1.0f / 45.0f));
            }
        }
    }
}

// ---------------- per-feature dual prefix sum (sum, sum^2), single pass ------
__global__ __launch_bounds__(256) void scan_kernel(
    const float* __restrict__ pooled_t,
    float* __restrict__ cs_t, float* __restrict__ cs2_t) {
    __shared__ float t1[256], t2[256];
    int f = blockIdx.x;
    int tid = threadIdx.x;
    const float* p = pooled_t + f * 8192;
    int base = tid * 32;
    float loc[32];
    float s1 = 0.f, s2 = 0.f;
#pragma unroll
    for (int i = 0; i < 32; ++i) {
        float v = p[base + i];
        loc[i] = v; s1 += v; s2 += v * v;
    }
    t1[tid] = s1; t2[tid] = s2;
    __syncthreads();
    for (int d = 1; d < 256; d <<= 1) {
        float a1 = (tid >= d) ? t1[tid - d] : 0.f;
        float a2 = (tid >= d) ? t2[tid - d] : 0.f;
        __syncthreads();
        t1[tid] += a1; t2[tid] += a2;
        __syncthreads();
    }
    float r1 = t1[tid] - s1, r2 = t2[tid] - s2;  // exclusive offsets
    float* c1 = cs_t + f * 8192;
    float* c2 = cs2_t + f * 8192;
#pragma unroll
    for (int i = 0; i < 32; ++i) {
        float v = loc[i];
        r1 += v; r2 += v * v;
        c1[base + i] = r1; c2[base + i] = r2;
    }
}

// ---------------- final: MFMA GEMM [Hb|est](8192x2336) @ Wb^T(16x2336) -------
// 32 rows/block, 256 blocks. Es tile built from L2-hot cs_t/cs2_t.
#define ESTRIDE 290
__global__ __launch_bounds__(256) void final_kernel(
    const unsigned short* __restrict__ Hb,
    const float* __restrict__ cs_t, const float* __restrict__ cs2_t,
    const unsigned short* __restrict__ Wb, const float* __restrict__ b_lin,
    float* __restrict__ out) {
    __shared__ unsigned short Es[32 * ESTRIDE];  // 18.1 KB
    __shared__ float comb[2 * 16 * 17];          // 2.1 KB
    int tid = threadIdx.x;
    int lane = tid & 63;
    int wave = tid >> 6;
    int b0 = blockIdx.x * 32;

    for (int i = tid; i < 135 * 32; i += 256) {
        int fj = i >> 5, r = i & 31;
        int f = fj / 3, j = fj - 3 * f;
        int b = b0 + r;
        int L = (j == 0) ? 32 : (j == 1) ? 128 : 512;
        const float* c1 = cs_t + f * 8192;
        const float* c2 = cs2_t + f * 8192;
        float a1 = c1[b], a2 = c2[b];
        float p1 = 0.f, p2 = 0.f;
        if (b >= L) { p1 = c1[b - L]; p2 = c2[b - L]; }
        float cnt = (float)((b + 1 < L) ? (b + 1) : L);
        float m = (a1 - p1) / cnt;
        float v = (a2 - p2) / cnt - m * m;
        int d0 = f * 6 + j * 2;
        Es[r * ESTRIDE + d0]     = f2bf(m);
        Es[r * ESTRIDE + d0 + 1] = f2bf(v);
    }
    for (int i = tid; i < 32 * 18; i += 256) {
        int r = i / 18, d = 270 + i % 18;
        Es[r * ESTRIDE + d] = 0;
    }
    __syncthreads();

    const int t = wave >> 1;
    const int kh = wave & 1;
    const int quad = lane >> 4;
    const int mrow = lane & 15;
    const int rowt = b0 + t * 16;

    f32x4 acc = f32x4{0.f, 0.f, 0.f, 0.f};
    const unsigned short* arow = Hb + (size_t)(rowt + mrow) * 2048 + kh * 1024 + quad * 8;
    const unsigned short* brow = Wb + (size_t)mrow * 2336 + kh * 1024 + quad * 8;
#pragma unroll 4
    for (int k = 0; k < 1024; k += 32) {
        s16x8 a = *(const s16x8*)(arow + k);
        s16x8 b = *(const s16x8*)(brow + k);
        acc = __builtin_amdgcn_mfma_f32_16x16x32_bf16(a, b, acc, 0, 0, 0);
    }
    if (kh) {
        const unsigned short* erow = Es + (t * 16 + mrow) * ESTRIDE + quad * 8;
        const unsigned short* wrow = Wb + (size_t)mrow * 2336 + 2048 + quad * 8;
#pragma unroll
        for (int k = 0; k < 288; k += 32) {
            s16x8 a = *(const s16x8*)(erow + k);
            s16x8 b = *(const s16x8*)(wrow + k);
            acc = __builtin_amdgcn_mfma_f32_16x16x32_bf16(a, b, acc, 0, 0, 0);
        }
    }

    float* cb = comb + t * 272;
    if (kh == 0) {
#pragma unroll
        for (int r = 0; r < 4; ++r) cb[(quad * 4 + r) * 17 + mrow] = acc[r];
    }
    __syncthreads();
    if (kh == 1) {
#pragma unroll
        for (int r = 0; r < 4; ++r) cb[(quad * 4 + r) * 17 + mrow] += acc[r];
    }
    __syncthreads();

    if (tid < 32) {
        const float* basep = comb + (tid >> 4) * 272 + (tid & 15) * 17;
        float lg[10];
        float mx = -1e30f;
#pragma unroll
        for (int c = 0; c < 10; ++c) {
            lg[c] = basep[c] + b_lin[c];
            mx = fmaxf(mx, lg[c]);
        }
        float s = 0.f;
#pragma unroll
        for (int c = 0; c < 10; ++c) { lg[c] = expf(lg[c] - mx); s += lg[c]; }
        float inv = 1.0f / s;
#pragma unroll
        for (int c = 0; c < 10; ++c) out[(size_t)(b0 + tid) * 10 + c] = lg[c] * inv;
    }
}

// ---------------- launch ----------------
extern "C" void kernel_launch(void* const* d_in, const int* in_sizes, int n_in,
                              void* d_out, int out_size, void* d_ws, size_t ws_size,
                              hipStream_t stream) {
    const float* x     = (const float*)d_in[0];   // (8192,1,2048)
    const float* W_ih  = (const float*)d_in[1];   // (2048,2048)
    // d_in[2] = W_hh unused: h0 == 0 so the recurrent term vanishes
    const float* b_ih  = (const float*)d_in[3];
    const float* b_hh  = (const float*)d_in[4];
    const float* W_lin = (const float*)d_in[5];   // (10, 2318)
    const float* b_lin = (const float*)d_in[6];
    float* out = (float*)d_out;

    char* ws = (char*)d_ws;
    unsigned short* xb  = (unsigned short*)(ws);                 // 33554432 B
    unsigned short* wb  = (unsigned short*)(ws + 33554432);      //  8388608 B
    unsigned short* Hb  = (unsigned short*)(ws + 41943040);      // 33554432 B
    float* pooled_t     = (float*)(ws + 75497472);               //  1474560 B
    float* cs_t         = (float*)(ws + 76972032);               //  1474560 B
    float* cs2_t        = (float*)(ws + 78446592);               //  1474560 B
    unsigned short* wlb = (unsigned short*)(ws + 79921152);      //    74752 B (~80 MB)

    prep_kernel<<<20986, 256, 0, stream>>>(x, W_ih, W_lin, xb, wb, wlb, pooled_t);
    dim3 ggrid(64, 16);
    gemm_tanh_kernel<<<ggrid, 256, 0, stream>>>(xb, wb, b_ih, b_hh, Hb, pooled_t);
    scan_kernel<<<45, 256, 0, stream>>>(pooled_t, cs_t, cs2_t);
    final_kernel<<<256, 256, 0, stream>>>(Hb, cs_t, cs2_t, wlb, b_lin, out);
}